// Round 1
// 396.716 us; speedup vs baseline: 1.0242x; 1.0242x over previous
//
#include <hip/hip_runtime.h>
#include <cstdint>
#include <cstddef>

typedef __bf16 bf16x8 __attribute__((ext_vector_type(8)));
typedef __bf16 bf16x4 __attribute__((ext_vector_type(4)));
typedef float f32x4 __attribute__((ext_vector_type(4)));
typedef unsigned short u16x4 __attribute__((ext_vector_type(4)));
typedef short s16x4 __attribute__((ext_vector_type(4)));
typedef short s16x8 __attribute__((ext_vector_type(8)));

// fp32 -> bf16 round-to-nearest-even
__device__ __forceinline__ unsigned short f2bf(float f) {
  union { float f; unsigned u; } v; v.f = f;
  unsigned r = (v.u + 0x7FFF + ((v.u >> 16) & 1)) >> 16;
  return (unsigned short)r;
}

// async global->LDS, 16B per lane
__device__ __forceinline__ void gl2lds16(const void* g, void* l) {
  __builtin_amdgcn_global_load_lds(
      (const __attribute__((address_space(1))) void*)g,
      (__attribute__((address_space(3))) void*)l,
      16, 0, 0);
}

// ---------------------------------------------------------------- prep
__global__ __launch_bounds__(256) void cast_f32_bf16(
    const float* __restrict__ in, unsigned short* __restrict__ out, int n) {
  int i = (blockIdx.x * 256 + threadIdx.x) * 4;
  if (i >= n) return;
  float4 v = *(const float4*)(in + i);
  u16x4 o;
  o[0] = f2bf(v.x); o[1] = f2bf(v.y); o[2] = f2bf(v.z); o[3] = f2bf(v.w);
  *(u16x4*)(out + i) = o;
}

__global__ __launch_bounds__(256) void transpose_cast(
    const float* __restrict__ in, unsigned short* __restrict__ out, int R, int C) {
  __shared__ float t[32][33];
  int c0 = blockIdx.x * 32, r0 = blockIdx.y * 32;
  int tx = threadIdx.x, ty = threadIdx.y;
#pragma unroll
  for (int j = 0; j < 4; ++j)
    t[ty + j * 8][tx] = in[(size_t)(r0 + ty + j * 8) * C + c0 + tx];
  __syncthreads();
#pragma unroll
  for (int j = 0; j < 4; ++j)
    out[(size_t)(c0 + ty + j * 8) * R + r0 + tx] = f2bf(t[tx][ty + j * 8]);
}

// key_padding_mask -> additive float; per-batch max unpadded key index+1.
__global__ __launch_bounds__(256) void prep_pad(
    const int* __restrict__ mask, float* __restrict__ padd, int* __restrict__ kmax, int n) {
  int i = blockIdx.x * 256 + threadIdx.x;
  if (i >= n) return;
  int mv = mask[i];
  padd[i] = mv ? -1e30f : 0.0f;
  int key = mv ? 0 : ((i & 2047) + 1);
#pragma unroll
  for (int off = 32; off; off >>= 1) key = max(key, __shfl_xor(key, off, 64));
  if ((threadIdx.x & 63) == 0) atomicMax(&kmax[i >> 11], key);  // i>>11 wave-uniform
}

// ---------------------------------------------------------------- GEMM (C = A[M,K] * B[N,K]^T)
template <int EPI>
__global__ __launch_bounds__(256) void gemm_bt(
    const unsigned short* __restrict__ A, const unsigned short* __restrict__ Bm,
    const float* __restrict__ bias, float* __restrict__ outF,
    unsigned short* __restrict__ Qb, unsigned short* __restrict__ Kb,
    unsigned short* __restrict__ Vt, int M, int N, int K) {
  __shared__ unsigned short As[128 * 32];
  __shared__ unsigned short Bs[128 * 32];
  const int tid = threadIdx.x;
  const int bm = blockIdx.x * 128;
  const int bn = blockIdx.y * 128;
  const int wave = tid >> 6, lane = tid & 63;
  const int wm = (wave >> 1) * 64, wn = (wave & 1) * 64;
  const int lr = lane & 15, lq = lane >> 4;

  f32x4 acc[4][4] = {};

  const int c0 = tid, c1 = tid + 256;
  const int rA0 = c0 >> 2, colA0 = (c0 & 3) * 8;
  const int rA1 = c1 >> 2, colA1 = (c1 & 3) * 8;

  for (int k0 = 0; k0 < K; k0 += 32) {
    __syncthreads();
    gl2lds16(A + (size_t)(bm + rA0) * K + k0 + colA0, As + c0 * 8);
    gl2lds16(A + (size_t)(bm + rA1) * K + k0 + colA1, As + c1 * 8);
    gl2lds16(Bm + (size_t)(bn + rA0) * K + k0 + colA0, Bs + c0 * 8);
    gl2lds16(Bm + (size_t)(bn + rA1) * K + k0 + colA1, Bs + c1 * 8);
    __syncthreads();
    bf16x8 af[4], bfr[4];
#pragma unroll
    for (int mi = 0; mi < 4; ++mi)
      af[mi] = *(const bf16x8*)(As + (wm + mi * 16 + lr) * 32 + lq * 8);
#pragma unroll
    for (int nj = 0; nj < 4; ++nj)
      bfr[nj] = *(const bf16x8*)(Bs + (wn + nj * 16 + lr) * 32 + lq * 8);
#pragma unroll
    for (int mi = 0; mi < 4; ++mi)
#pragma unroll
      for (int nj = 0; nj < 4; ++nj)
        acc[mi][nj] = __builtin_amdgcn_mfma_f32_16x16x32_bf16(af[mi], bfr[nj], acc[mi][nj], 0, 0, 0);
  }

#pragma unroll
  for (int mi = 0; mi < 4; ++mi) {
#pragma unroll
    for (int nj = 0; nj < 4; ++nj) {
#pragma unroll
      for (int r = 0; r < 4; ++r) {
        int m = bm + wm + mi * 16 + lq * 4 + r;
        int n = bn + wn + nj * 16 + lr;
        float v = acc[mi][nj][r] + bias[n];
        if (EPI == 0) {
          int b = m >> 11, t = m & 2047;
          int part = n >> 10, d = n & 1023;
          int h = d >> 6, hd = d & 63;
          size_t qk = ((size_t)(b * 16 + h) * 2048 + t) * 64 + hd;
          // fold softmax scale 1/sqrt(64) and log2(e) into Q
          if (part == 0)      Qb[qk] = f2bf(v * 0.18033688011112042f);
          else if (part == 1) Kb[qk] = f2bf(v);
          else                Vt[((size_t)(b * 16 + h) * 64 + hd) * 2048 + t] = f2bf(v);
        } else {
          outF[(size_t)m * N + n] = v;
        }
      }
    }
  }
}

// ---------------------------------------------------------------- flash attention
// S^T = K Q^T: C-layout (key=4*lq+r, query=lr) is directly the A-operand layout
// for PV — no LDS, no barriers.
// Round 1 change: batch-issue ALL K-frag loads for a chunk before the QK MFMAs,
// and ALL V-frag loads before the softmax (V latency hides under exp2 work).
// Previously each load was issued next to its consumer -> ~56 serialized
// ~500-cycle L2 latencies per chunk (measured 29.5k cyc/chunk vs ~900 compute).
// Also: PV via mfma_16x16x32 on paired key-slots (half the MFMA issues; valid
// since A and B share any key->(lane,reg) permutation), and padding addend
// skipped for chunks fully below kmax (all of them, for this mask).

__device__ __forceinline__ void process_tile32(
    const unsigned short* __restrict__ Qh, const unsigned short* __restrict__ Kh,
    const unsigned short* __restrict__ Vh, const float* __restrict__ pb,
    unsigned short* __restrict__ ctxBase, int q0, int kcapR, int kmaxRaw,
    int lr, int lq, int bsrc) {
  bf16x8 qf[2][2];
#pragma unroll
  for (int qt = 0; qt < 2; ++qt) {
    const unsigned short* qp = Qh + (size_t)(q0 + qt * 16 + lr) * 64 + lq * 8;
    qf[qt][0] = *(const bf16x8*)(qp);
    qf[qt][1] = *(const bf16x8*)(qp + 32);
  }
  f32x4 O[2][4] = {};
  float m[2] = {-1e30f, -1e30f}, l[2] = {0.f, 0.f};
  const bool diag = (q0 < kcapR);
  const int last = diag ? (q0 >> 7) : ((kcapR >> 7) - 1);

  for (int i = 0; i <= last; ++i) {
    const int kc = i << 7;

    // ---- batch-issue all 16 K-fragment loads (memory-level parallelism)
    bf16x8 kf[8][2];
#pragma unroll
    for (int t = 0; t < 8; ++t) {
      const unsigned short* kp = Kh + (size_t)(kc + t * 16 + lr) * 64 + lq * 8;
      kf[t][0] = *(const bf16x8*)(kp);
      kf[t][1] = *(const bf16x8*)(kp + 32);
    }

    // ---- QK^T over 128 keys (8 key-tiles of 16); both q-tiles share K frags
    f32x4 S[2][8];
#pragma unroll
    for (int t = 0; t < 8; ++t) {
      f32x4 s0 = {}, s1 = {};
      s0 = __builtin_amdgcn_mfma_f32_16x16x32_bf16(kf[t][0], qf[0][0], s0, 0, 0, 0);
      s0 = __builtin_amdgcn_mfma_f32_16x16x32_bf16(kf[t][1], qf[0][1], s0, 0, 0, 0);
      s1 = __builtin_amdgcn_mfma_f32_16x16x32_bf16(kf[t][0], qf[1][0], s1, 0, 0, 0);
      s1 = __builtin_amdgcn_mfma_f32_16x16x32_bf16(kf[t][1], qf[1][1], s1, 0, 0, 0);
      S[0][t] = s0;
      S[1][t] = s1;
    }

    // ---- batch-issue all 32 V-fragment loads; latency hides under softmax
    s16x4 vfr[4][8];
#pragma unroll
    for (int nj = 0; nj < 4; ++nj) {
      const unsigned short* vp = Vh + (size_t)(nj * 16 + lr) * 2048 + kc + 4 * lq;
#pragma unroll
      for (int t = 0; t < 8; ++t) vfr[nj][t] = *(const s16x4*)(vp + t * 16);
    }

    // padding addend only needed on chunks that touch keys >= kmax
    if (kc + 128 > kmaxRaw) {
#pragma unroll
      for (int t = 0; t < 8; ++t) {
        float4 pd = *(const float4*)(pb + kc + t * 16 + 4 * lq);
#pragma unroll
        for (int qt = 0; qt < 2; ++qt) {
          S[qt][t][0] += pd.x; S[qt][t][1] += pd.y;
          S[qt][t][2] += pd.z; S[qt][t][3] += pd.w;
        }
      }
    }
    if (diag && i == last) {
#pragma unroll
      for (int qt = 0; qt < 2; ++qt) {
        const int q = q0 + qt * 16 + lr;
#pragma unroll
        for (int t = 0; t < 8; ++t)
#pragma unroll
          for (int r = 0; r < 4; ++r) {
            int key = kc + t * 16 + 4 * lq + r;
            if (key > q) S[qt][t][r] = -1e30f;
          }
      }
    }

    // ---- online softmax per q-tile (row = query = lr); two independent chains
    float al[2];
#pragma unroll
    for (int qt = 0; qt < 2; ++qt) {
      f32x4 vmx = S[qt][0];
#pragma unroll
      for (int t = 1; t < 8; ++t) {
        vmx[0] = fmaxf(vmx[0], S[qt][t][0]); vmx[1] = fmaxf(vmx[1], S[qt][t][1]);
        vmx[2] = fmaxf(vmx[2], S[qt][t][2]); vmx[3] = fmaxf(vmx[3], S[qt][t][3]);
      }
      float mx = fmaxf(fmaxf(vmx[0], vmx[1]), fmaxf(vmx[2], vmx[3]));
      mx = fmaxf(mx, __shfl_xor(mx, 16, 64));
      mx = fmaxf(mx, __shfl_xor(mx, 32, 64));
      float mnew = fmaxf(m[qt], mx);
      float a = __builtin_amdgcn_exp2f(m[qt] - mnew);
      m[qt] = mnew;
      f32x4 vs = {};
#pragma unroll
      for (int t = 0; t < 8; ++t) {
#pragma unroll
        for (int r = 0; r < 4; ++r) {
          float p = __builtin_amdgcn_exp2f(S[qt][t][r] - mnew);
          S[qt][t][r] = p;
          vs[r] += p;
        }
      }
      float rs = (vs[0] + vs[1]) + (vs[2] + vs[3]);
      rs += __shfl_xor(rs, 16, 64);
      rs += __shfl_xor(rs, 32, 64);
      l[qt] = l[qt] * a + rs;
      al[qt] = a;
    }
    // alpha: query=lr domain -> query=4*lq+r domain; rescale O
#pragma unroll
    for (int qt = 0; qt < 2; ++qt)
#pragma unroll
      for (int r = 0; r < 4; ++r) {
        float a = __shfl(al[qt], bsrc + r, 64);
#pragma unroll
        for (int nj = 0; nj < 4; ++nj) O[qt][nj][r] *= a;
      }

    // ---- P cvt to bf16 A-frags, paired over key-slots (2tt, 2tt+1)
    bf16x8 pf[2][4];
#pragma unroll
    for (int qt = 0; qt < 2; ++qt)
#pragma unroll
      for (int tt = 0; tt < 4; ++tt) {
        bf16x8 p8;
#pragma unroll
        for (int r = 0; r < 4; ++r) {
          p8[r]     = (__bf16)S[qt][2 * tt][r];
          p8[r + 4] = (__bf16)S[qt][2 * tt + 1][r];
        }
        pf[qt][tt] = p8;
      }

    // ---- PV via 16x16x32: O[query=4*lq+r][hd=lr+nj*16]; V frags shared by
    //      both q-tiles; A/B share the (lq,reg)->key permutation, so valid.
#pragma unroll
    for (int nj = 0; nj < 4; ++nj) {
#pragma unroll
      for (int tt = 0; tt < 4; ++tt) {
        s16x4 va = vfr[nj][2 * tt], vb = vfr[nj][2 * tt + 1];
        s16x8 vv;
        vv[0] = va[0]; vv[1] = va[1]; vv[2] = va[2]; vv[3] = va[3];
        vv[4] = vb[0]; vv[5] = vb[1]; vv[6] = vb[2]; vv[7] = vb[3];
        bf16x8 v8 = __builtin_bit_cast(bf16x8, vv);
        O[0][nj] = __builtin_amdgcn_mfma_f32_16x16x32_bf16(pf[0][tt], v8, O[0][nj], 0, 0, 0);
        O[1][nj] = __builtin_amdgcn_mfma_f32_16x16x32_bf16(pf[1][tt], v8, O[1][nj], 0, 0, 0);
      }
    }
  }

  float linv0 = 1.0f / l[0], linv1 = 1.0f / l[1];
#pragma unroll
  for (int r = 0; r < 4; ++r) {
    float li0 = __shfl(linv0, bsrc + r, 64);
    float li1 = __shfl(linv1, bsrc + r, 64);
    int q = q0 + 4 * lq + r;
    unsigned short* cp0 = ctxBase + (size_t)q * 1024 + lr;
    unsigned short* cp1 = cp0 + (size_t)16 * 1024;
#pragma unroll
    for (int nj = 0; nj < 4; ++nj) {
      cp0[nj * 16] = f2bf(O[0][nj][r] * li0);
      cp1[nj * 16] = f2bf(O[1][nj][r] * li1);
    }
  }
}

__global__ __launch_bounds__(256, 2) void flash_attn(
    const unsigned short* __restrict__ Qb, const unsigned short* __restrict__ Kb,
    const unsigned short* __restrict__ Vt, const float* __restrict__ padd,
    const int* __restrict__ kmax, unsigned short* __restrict__ ctx) {
  const int bid = blockIdx.x;      // 512 blocks
  const int pg = bid >> 6;         // 0..7
  const int bh = bid & 63;
  const int b = bh >> 4, h = bh & 15;
  const int wave = threadIdx.x >> 6, lane = threadIdx.x & 63;
  const int lr = lane & 15, lq = lane >> 4;
  const int bsrc = 20 * lq;        // lane with lr == 4*lq+r
  const int pp = pg * 4 + wave;    // 0..31: pair (63-pp, pp) of 32-row tiles

  const unsigned short* Qh = Qb + (size_t)bh * 2048 * 64;
  const unsigned short* Kh = Kb + (size_t)bh * 2048 * 64;
  const unsigned short* Vh = Vt + (size_t)bh * 64 * 2048;
  const float* pb = padd + b * 2048;
  unsigned short* ctxBase = ctx + ((size_t)b * 2048) * 1024 + h * 64;
  const int kmaxRaw = kmax[b];
  const int kcapR = (kmaxRaw + 127) & ~127;

  process_tile32(Qh, Kh, Vh, pb, ctxBase, (63 - pp) * 32, kcapR, kmaxRaw, lr, lq, bsrc);
  process_tile32(Qh, Kh, Vh, pb, ctxBase, pp * 32, kcapR, kmaxRaw, lr, lq, bsrc);
}

// ---------------------------------------------------------------- launch
extern "C" void kernel_launch(void* const* d_in, const int* in_sizes, int n_in,
                              void* d_out, int out_size, void* d_ws, size_t ws_size,
                              hipStream_t stream) {
  const float* x    = (const float*)d_in[0];
  const float* Wqkv = (const float*)d_in[1];
  const float* bqkv = (const float*)d_in[2];
  const float* Wo   = (const float*)d_in[3];
  const float* bo   = (const float*)d_in[4];
  const int*   mask = (const int*)d_in[5];
  float* out = (float*)d_out;

  unsigned short* ws = (unsigned short*)d_ws;
  const size_t SZ_X = (size_t)8192 * 1024;  // B*T*D
  unsigned short* xb    = ws;                                   // 16 MB, reused as ctx
  unsigned short* WqkvT = xb + SZ_X;                            // 6 MB
  unsigned short* WoT   = WqkvT + (size_t)3072 * 1024;          // 2 MB
  unsigned short* Qb    = WoT + (size_t)1024 * 1024;            // 16 MB
  unsigned short* Kb    = Qb + SZ_X;                            // 16 MB
  unsigned short* Vt    = Kb + SZ_X;                            // 16 MB
  float*          padd  = (float*)(Vt + SZ_X);                  // 32 KB
  int*            kmax  = (int*)(padd + 8192);                  // 16 B
  unsigned short* ctx   = xb;  // xb dead after GEMM1

  hipMemsetAsync(kmax, 0, 4 * sizeof(int), stream);
  cast_f32_bf16<<<8192, 256, 0, stream>>>(x, xb, (int)SZ_X);
  transpose_cast<<<dim3(96, 32), dim3(32, 8), 0, stream>>>(Wqkv, WqkvT, 1024, 3072);
  transpose_cast<<<dim3(32, 32), dim3(32, 8), 0, stream>>>(Wo, WoT, 1024, 1024);
  prep_pad<<<32, 256, 0, stream>>>(mask, padd, kmax, 8192);
  gemm_bt<0><<<dim3(64, 24), 256, 0, stream>>>(xb, WqkvT, bqkv, nullptr, Qb, Kb, Vt,
                                               8192, 3072, 1024);
  flash_attn<<<512, 256, 0, stream>>>(Qb, Kb, Vt, padd, kmax, ctx);
  gemm_bt<1><<<dim3(64, 8), 256, 0, stream>>>(ctx, WoT, bo, out, nullptr, nullptr, nullptr,
                                              8192, 1024, 1024);
}

// Round 3
// 296.224 us; speedup vs baseline: 1.3717x; 1.3392x over previous
//
#include <hip/hip_runtime.h>
#include <cstdint>
#include <cstddef>

typedef __bf16 bf16x8 __attribute__((ext_vector_type(8)));
typedef float f32x4 __attribute__((ext_vector_type(4)));
typedef float f32x16 __attribute__((ext_vector_type(16)));
typedef unsigned short u16x4 __attribute__((ext_vector_type(4)));
typedef unsigned int u32x4 __attribute__((ext_vector_type(4)));

// fp32 -> bf16 round-to-nearest-even
__device__ __forceinline__ unsigned short f2bf(float f) {
  union { float f; unsigned u; } v; v.f = f;
  unsigned r = (v.u + 0x7FFF + ((v.u >> 16) & 1)) >> 16;
  return (unsigned short)r;
}

// pack two floats into one u32 of 2 bf16
__device__ __forceinline__ unsigned pkbf(float x, float y) {
  unsigned short a = __builtin_bit_cast(unsigned short, (__bf16)x);
  unsigned short b = __builtin_bit_cast(unsigned short, (__bf16)y);
  return (unsigned)a | ((unsigned)b << 16);
}

// async global->LDS, 16B per lane
__device__ __forceinline__ void gl2lds16(const void* g, void* l) {
  __builtin_amdgcn_global_load_lds(
      (const __attribute__((address_space(1))) void*)g,
      (__attribute__((address_space(3))) void*)l,
      16, 0, 0);
}

// ---------------------------------------------------------------- prep
__global__ __launch_bounds__(256) void cast_f32_bf16(
    const float* __restrict__ in, unsigned short* __restrict__ out, int n) {
  int i = (blockIdx.x * 256 + threadIdx.x) * 4;
  if (i >= n) return;
  float4 v = *(const float4*)(in + i);
  u16x4 o;
  o[0] = f2bf(v.x); o[1] = f2bf(v.y); o[2] = f2bf(v.z); o[3] = f2bf(v.w);
  *(u16x4*)(out + i) = o;
}

__global__ __launch_bounds__(256) void transpose_cast(
    const float* __restrict__ in, unsigned short* __restrict__ out, int R, int C) {
  __shared__ float t[32][33];
  int c0 = blockIdx.x * 32, r0 = blockIdx.y * 32;
  int tx = threadIdx.x, ty = threadIdx.y;
#pragma unroll
  for (int j = 0; j < 4; ++j)
    t[ty + j * 8][tx] = in[(size_t)(r0 + ty + j * 8) * C + c0 + tx];
  __syncthreads();
#pragma unroll
  for (int j = 0; j < 4; ++j)
    out[(size_t)(c0 + ty + j * 8) * R + r0 + tx] = f2bf(t[tx][ty + j * 8]);
}

// key_padding_mask -> per-batch max unpadded key index+1 (suffix-mask semantics).
__global__ __launch_bounds__(256) void prep_pad(
    const int* __restrict__ mask, float* __restrict__ padd, int* __restrict__ kmax, int n) {
  int i = blockIdx.x * 256 + threadIdx.x;
  if (i >= n) return;
  int mv = mask[i];
  padd[i] = mv ? -1e30f : 0.0f;
  int key = mv ? 0 : ((i & 2047) + 1);
#pragma unroll
  for (int off = 32; off; off >>= 1) key = max(key, __shfl_xor(key, off, 64));
  if ((threadIdx.x & 63) == 0) atomicMax(&kmax[i >> 11], key);  // i>>11 wave-uniform
}

// ---------------------------------------------------------------- GEMM (C = A[M,K] * B[N,K]^T)
template <int EPI>
__global__ __launch_bounds__(256) void gemm_bt(
    const unsigned short* __restrict__ A, const unsigned short* __restrict__ Bm,
    const float* __restrict__ bias, float* __restrict__ outF,
    unsigned short* __restrict__ Qb, unsigned short* __restrict__ Kb,
    unsigned short* __restrict__ Vt, int M, int N, int K) {
  __shared__ unsigned short As[128 * 32];
  __shared__ unsigned short Bs[128 * 32];
  const int tid = threadIdx.x;
  const int bm = blockIdx.x * 128;
  const int bn = blockIdx.y * 128;
  const int wave = tid >> 6, lane = tid & 63;
  const int wm = (wave >> 1) * 64, wn = (wave & 1) * 64;
  const int lr = lane & 15, lq = lane >> 4;

  f32x4 acc[4][4] = {};

  const int c0 = tid, c1 = tid + 256;
  const int rA0 = c0 >> 2, colA0 = (c0 & 3) * 8;
  const int rA1 = c1 >> 2, colA1 = (c1 & 3) * 8;

  for (int k0 = 0; k0 < K; k0 += 32) {
    __syncthreads();
    gl2lds16(A + (size_t)(bm + rA0) * K + k0 + colA0, As + c0 * 8);
    gl2lds16(A + (size_t)(bm + rA1) * K + k0 + colA1, As + c1 * 8);
    gl2lds16(Bm + (size_t)(bn + rA0) * K + k0 + colA0, Bs + c0 * 8);
    gl2lds16(Bm + (size_t)(bn + rA1) * K + k0 + colA1, Bs + c1 * 8);
    __syncthreads();
    bf16x8 af[4], bfr[4];
#pragma unroll
    for (int mi = 0; mi < 4; ++mi)
      af[mi] = *(const bf16x8*)(As + (wm + mi * 16 + lr) * 32 + lq * 8);
#pragma unroll
    for (int nj = 0; nj < 4; ++nj)
      bfr[nj] = *(const bf16x8*)(Bs + (wn + nj * 16 + lr) * 32 + lq * 8);
#pragma unroll
    for (int mi = 0; mi < 4; ++mi)
#pragma unroll
      for (int nj = 0; nj < 4; ++nj)
        acc[mi][nj] = __builtin_amdgcn_mfma_f32_16x16x32_bf16(af[mi], bfr[nj], acc[mi][nj], 0, 0, 0);
  }

#pragma unroll
  for (int mi = 0; mi < 4; ++mi) {
#pragma unroll
    for (int nj = 0; nj < 4; ++nj) {
#pragma unroll
      for (int r = 0; r < 4; ++r) {
        int m = bm + wm + mi * 16 + lq * 4 + r;
        int n = bn + wn + nj * 16 + lr;
        float v = acc[mi][nj][r] + bias[n];
        if (EPI == 0) {
          int b = m >> 11, t = m & 2047;
          int part = n >> 10, d = n & 1023;
          int h = d >> 6, hd = d & 63;
          size_t qk = ((size_t)(b * 16 + h) * 2048 + t) * 64 + hd;
          // fold softmax scale 1/sqrt(64) and log2(e) into Q
          if (part == 0)      Qb[qk] = f2bf(v * 0.18033688011112042f);
          else if (part == 1) Kb[qk] = f2bf(v);
          else                Vt[((size_t)(b * 16 + h) * 64 + hd) * 2048 + t] = f2bf(v);
        } else {
          outF[(size_t)m * N + n] = v;
        }
      }
    }
  }
}

// ---------------------------------------------------------------- flash attention
// LDS-staged, double-buffered, 32x32 MFMA, lane-local softmax.
//  - block = 4 waves x 64 q-rows = 256 q-rows; 512 blocks (64 bh x 8 q-superblocks,
//    paired jj / 7-jj across grid halves for CU load balance; bid%8==bh%8 keeps a
//    head's K/V on one XCD L2).
//  - per 64-key chunk: K tile [64k][64d] (8KB) + V tile [64hd][64k] (8KB) staged
//    via global_load_lds (async), double-buffered (32KB LDS). XOR swizzle
//    (slot ^= row&7, 16B granularity) applied on the GLOBAL source (LDS dest
//    must stay linear for global_load_lds) and on the ds_read side.
//  - S^T = K·Q^T via mfma_f32_32x32x16_bf16: S cols = q = lane&31 -> softmax
//    stats lane-local; O^T = V^T·P keeps q lane-local (no alpha broadcast).
// Round 3 fix: STAGE macro '(kcS + row)' expanded '(i+1)<<6 + row' as
// '(i+1)<<(6+row)' (shift binds looser than +) -> garbage addresses -> GPU
// memory fault. Replaced macro with a lambda; no other changes.

__global__ __launch_bounds__(256, 2) void flash_attn(
    const unsigned short* __restrict__ Qb, const unsigned short* __restrict__ Kb,
    const unsigned short* __restrict__ Vt, const int* __restrict__ kmax,
    unsigned short* __restrict__ ctx) {
  __shared__ unsigned short lds[16384];  // [buf][ K 4096 | V 4096 ] elements

  const int bid = blockIdx.x;            // 512 blocks
  const int halfg = bid >> 8;            // 0/1
  const int rb = bid & 255;
  const int bh = rb & 63;                // bid%8 == bh%8 -> XCD locality
  const int jj = rb >> 6;                // 0..3
  const int j = halfg ? (7 - jj) : jj;   // q-superblock, paired for balance
  const int blockQ = j << 8;
  const int b = bh >> 4, h = bh & 15;
  const int tid = threadIdx.x;
  const int wave = tid >> 6, lane = tid & 63;
  const int l31 = lane & 31, hi = lane >> 5;
  const int qw = blockQ + wave * 64;     // wave's 64 q-rows

  const unsigned short* Qh = Qb + (size_t)bh * 2048 * 64;
  const unsigned short* Kh = Kb + (size_t)bh * 2048 * 64;
  const unsigned short* Vh = Vt + (size_t)bh * 64 * 2048;
  unsigned short* ctxBase = ctx + (size_t)b * 2048 * 1024 + h * 64;

  const int kmaxRaw = kmax[b];
  const int kcapC = (kmaxRaw + 63) >> 6;                     // chunks by padding
  const int lastB = min((blockQ + 255) >> 6, kcapC - 1);     // block's last chunk
  const int diagI = qw >> 6;                                 // wave's diagonal chunk

  // Q fragments: B-operand of QK (n=q=l31, k=d=8*hi+j), 16B contiguous
  bf16x8 qf[2][4];
#pragma unroll
  for (int qt = 0; qt < 2; ++qt)
#pragma unroll
    for (int ds = 0; ds < 4; ++ds)
      qf[qt][ds] = *(const bf16x8*)(Qh + (size_t)(qw + qt * 32 + l31) * 64 + ds * 16 + hi * 8);

  f32x16 O[2][2] = {};                   // [qt][mt]  O^T: row=hd(reg), col=q(lane)
  float mR[2] = {-1e30f, -1e30f}, lR[2] = {0.f, 0.f};

  const int trow = tid >> 3, tslot = tid & 7;

  // stage one 64-key chunk (K 8KB + V 8KB) into buf; inverse-swizzled source
  auto stage = [&](int bufI, int kcS) {
#pragma unroll
    for (int rnd = 0; rnd < 2; ++rnd) {
      int row = rnd * 32 + trow;
      int sl = tslot ^ (row & 7);
      gl2lds16(Kh + (size_t)(kcS + row) * 64 + sl * 8,
               lds + bufI * 8192 + rnd * 2048 + tid * 8);
      gl2lds16(Vh + (size_t)row * 2048 + kcS + sl * 8,
               lds + bufI * 8192 + 4096 + rnd * 2048 + tid * 8);
    }
  };

  stage(0, 0);
  int cur = 0;
  for (int i = 0; i <= lastB; ++i) {
    __syncthreads();  // drains vmcnt -> buf[cur] staged; prior reads of buf[cur^1] done
    if (i < lastB) stage(cur ^ 1, (i + 1) << 6);
    if (i <= diagI) {
      const int kc = i << 6;
      const unsigned short* Ksb = lds + cur * 8192;
      const unsigned short* Vsb = Ksb + 4096;

      // ---- QK^T: S^T[key][q], A=K (m=key), B=Q^T (n=q)
      f32x16 S[2][2] = {};  // [qt][kt]
      __builtin_amdgcn_s_setprio(1);
#pragma unroll
      for (int kt = 0; kt < 2; ++kt) {
        const int row = kt * 32 + l31;
        const int rx = row & 7;
#pragma unroll
        for (int ds = 0; ds < 4; ++ds) {
          bf16x8 kfr = *(const bf16x8*)(Ksb + row * 64 + (((ds * 2 + hi) ^ rx) << 3));
          S[0][kt] = __builtin_amdgcn_mfma_f32_32x32x16_bf16(kfr, qf[0][ds], S[0][kt], 0, 0, 0);
          S[1][kt] = __builtin_amdgcn_mfma_f32_32x32x16_bf16(kfr, qf[1][ds], S[1][kt], 0, 0, 0);
        }
      }
      __builtin_amdgcn_s_setprio(0);

      // ---- mask (causal on diag chunk; padding on boundary chunk)
      const bool isDiag = (i == diagI);
      if (isDiag || (kc + 64 > kmaxRaw)) {
#pragma unroll
        for (int qt = 0; qt < 2; ++qt) {
          const int q = qw + qt * 32 + l31;
#pragma unroll
          for (int kt = 0; kt < 2; ++kt)
#pragma unroll
            for (int rr = 0; rr < 16; ++rr) {
              int key = kc + kt * 32 + (rr & 3) + ((rr >> 2) << 3) + (hi << 2);
              if ((isDiag && key > q) || key >= kmaxRaw) S[qt][kt][rr] = -1e30f;
            }
        }
      }

      // ---- online softmax (q lane-local) + P pack
      bf16x8 pf[2][2][2];  // [qt][kt][ks]
#pragma unroll
      for (int qt = 0; qt < 2; ++qt) {
        float v[16];
#pragma unroll
        for (int rr = 0; rr < 16; ++rr) v[rr] = fmaxf(S[qt][0][rr], S[qt][1][rr]);
#pragma unroll
        for (int st = 8; st; st >>= 1)
#pragma unroll
          for (int rr = 0; rr < st; ++rr) v[rr] = fmaxf(v[rr], v[rr + st]);
        float mx = fmaxf(v[0], __shfl_xor(v[0], 32, 64));
        float mnew = fmaxf(mR[qt], mx);
        float a = __builtin_amdgcn_exp2f(mR[qt] - mnew);
        mR[qt] = mnew;
#pragma unroll
        for (int kt = 0; kt < 2; ++kt)
#pragma unroll
          for (int rr = 0; rr < 16; ++rr)
            S[qt][kt][rr] = __builtin_amdgcn_exp2f(S[qt][kt][rr] - mnew);
        float sacc[16];
#pragma unroll
        for (int rr = 0; rr < 16; ++rr) sacc[rr] = S[qt][0][rr] + S[qt][1][rr];
#pragma unroll
        for (int st = 8; st; st >>= 1)
#pragma unroll
          for (int rr = 0; rr < st; ++rr) sacc[rr] += sacc[rr + st];
        float sum = sacc[0] + __shfl_xor(sacc[0], 32, 64);
        lR[qt] = lR[qt] * a + sum;
#pragma unroll
        for (int mt = 0; mt < 2; ++mt)
#pragma unroll
          for (int rr = 0; rr < 16; ++rr) O[qt][mt][rr] *= a;
        // pack P into PV B-frags (n=q=l31, k=key=8*hi+j within 16-key step)
#pragma unroll
        for (int kt = 0; kt < 2; ++kt) {
          unsigned a0 = pkbf(S[qt][kt][0], S[qt][kt][1]);
          unsigned a1 = pkbf(S[qt][kt][2], S[qt][kt][3]);
          unsigned b0 = pkbf(S[qt][kt][4], S[qt][kt][5]);
          unsigned b1 = pkbf(S[qt][kt][6], S[qt][kt][7]);
          unsigned c0 = pkbf(S[qt][kt][8], S[qt][kt][9]);
          unsigned c1 = pkbf(S[qt][kt][10], S[qt][kt][11]);
          unsigned d0 = pkbf(S[qt][kt][12], S[qt][kt][13]);
          unsigned d1 = pkbf(S[qt][kt][14], S[qt][kt][15]);
          unsigned s0 = __shfl_xor(hi ? a0 : b0, 32, 64);
          unsigned s1 = __shfl_xor(hi ? a1 : b1, 32, 64);
          unsigned s2 = __shfl_xor(hi ? c0 : d0, 32, 64);
          unsigned s3 = __shfl_xor(hi ? c1 : d1, 32, 64);
          u32x4 f0, f1;
          f0[0] = hi ? s0 : a0; f0[1] = hi ? s1 : a1;
          f0[2] = hi ? b0 : s0; f0[3] = hi ? b1 : s1;
          f1[0] = hi ? s2 : c0; f1[1] = hi ? s3 : c1;
          f1[2] = hi ? d0 : s2; f1[3] = hi ? d1 : s3;
          pf[qt][kt][0] = __builtin_bit_cast(bf16x8, f0);
          pf[qt][kt][1] = __builtin_bit_cast(bf16x8, f1);
        }
      }

      // ---- PV: O^T += V^T · P   (A=V^T: m=hd, k=key; B=P)
      __builtin_amdgcn_s_setprio(1);
      const int vx = l31 & 7;
#pragma unroll
      for (int kt = 0; kt < 2; ++kt)
#pragma unroll
        for (int ks = 0; ks < 2; ++ks) {
          const int slot = kt * 4 + ks * 2 + hi;
          bf16x8 v0 = *(const bf16x8*)(Vsb + l31 * 64 + ((slot ^ vx) << 3));
          bf16x8 v1 = *(const bf16x8*)(Vsb + (32 + l31) * 64 + ((slot ^ vx) << 3));
          O[0][0] = __builtin_amdgcn_mfma_f32_32x32x16_bf16(v0, pf[0][kt][ks], O[0][0], 0, 0, 0);
          O[0][1] = __builtin_amdgcn_mfma_f32_32x32x16_bf16(v1, pf[0][kt][ks], O[0][1], 0, 0, 0);
          O[1][0] = __builtin_amdgcn_mfma_f32_32x32x16_bf16(v0, pf[1][kt][ks], O[1][0], 0, 0, 0);
          O[1][1] = __builtin_amdgcn_mfma_f32_32x32x16_bf16(v1, pf[1][kt][ks], O[1][1], 0, 0, 0);
        }
      __builtin_amdgcn_s_setprio(0);
    }
    cur ^= 1;
  }

  // ---- epilogue: O^T normalize, write ctx[q][h*64+hd] (q lane-local)
#pragma unroll
  for (int qt = 0; qt < 2; ++qt) {
    float linv = 1.0f / lR[qt];
    const int q = qw + qt * 32 + l31;
    unsigned short* cp = ctxBase + (size_t)q * 1024;
#pragma unroll
    for (int mt = 0; mt < 2; ++mt)
#pragma unroll
      for (int g = 0; g < 4; ++g) {
        u16x4 o4;
#pragma unroll
        for (int rr = 0; rr < 4; ++rr) o4[rr] = f2bf(O[qt][mt][4 * g + rr] * linv);
        *(u16x4*)(cp + mt * 32 + 8 * g + 4 * hi) = o4;
      }
  }
}

// ---------------------------------------------------------------- launch
extern "C" void kernel_launch(void* const* d_in, const int* in_sizes, int n_in,
                              void* d_out, int out_size, void* d_ws, size_t ws_size,
                              hipStream_t stream) {
  const float* x    = (const float*)d_in[0];
  const float* Wqkv = (const float*)d_in[1];
  const float* bqkv = (const float*)d_in[2];
  const float* Wo   = (const float*)d_in[3];
  const float* bo   = (const float*)d_in[4];
  const int*   mask = (const int*)d_in[5];
  float* out = (float*)d_out;

  unsigned short* ws = (unsigned short*)d_ws;
  const size_t SZ_X = (size_t)8192 * 1024;  // B*T*D
  unsigned short* xb    = ws;                                   // 16 MB, reused as ctx
  unsigned short* WqkvT = xb + SZ_X;                            // 6 MB
  unsigned short* WoT   = WqkvT + (size_t)3072 * 1024;          // 2 MB
  unsigned short* Qb    = WoT + (size_t)1024 * 1024;            // 16 MB
  unsigned short* Kb    = Qb + SZ_X;                            // 16 MB
  unsigned short* Vt    = Kb + SZ_X;                            // 16 MB
  float*          padd  = (float*)(Vt + SZ_X);                  // 32 KB
  int*            kmax  = (int*)(padd + 8192);                  // 16 B
  unsigned short* ctx   = xb;  // xb dead after GEMM1

  hipMemsetAsync(kmax, 0, 4 * sizeof(int), stream);
  cast_f32_bf16<<<8192, 256, 0, stream>>>(x, xb, (int)SZ_X);
  transpose_cast<<<dim3(96, 32), dim3(32, 8), 0, stream>>>(Wqkv, WqkvT, 1024, 3072);
  transpose_cast<<<dim3(32, 32), dim3(32, 8), 0, stream>>>(Wo, WoT, 1024, 1024);
  prep_pad<<<32, 256, 0, stream>>>(mask, padd, kmax, 8192);
  gemm_bt<0><<<dim3(64, 24), 256, 0, stream>>>(xb, WqkvT, bqkv, nullptr, Qb, Kb, Vt,
                                               8192, 3072, 1024);
  flash_attn<<<512, 256, 0, stream>>>(Qb, Kb, Vt, kmax, ctx);
  gemm_bt<1><<<dim3(64, 8), 256, 0, stream>>>(ctx, WoT, bo, out, nullptr, nullptr, nullptr,
                                              8192, 1024, 1024);
}

// Round 4
// 273.717 us; speedup vs baseline: 1.4845x; 1.0822x over previous
//
#include <hip/hip_runtime.h>
#include <cstdint>
#include <cstddef>

typedef __bf16 bf16x8 __attribute__((ext_vector_type(8)));
typedef float f32x4 __attribute__((ext_vector_type(4)));
typedef float f32x16 __attribute__((ext_vector_type(16)));
typedef unsigned short u16x4 __attribute__((ext_vector_type(4)));
typedef unsigned int u32x4 __attribute__((ext_vector_type(4)));

// fp32 -> bf16 round-to-nearest-even
__device__ __forceinline__ unsigned short f2bf(float f) {
  union { float f; unsigned u; } v; v.f = f;
  unsigned r = (v.u + 0x7FFF + ((v.u >> 16) & 1)) >> 16;
  return (unsigned short)r;
}

// pack two floats into one u32 of 2 bf16
__device__ __forceinline__ unsigned pkbf(float x, float y) {
  unsigned short a = __builtin_bit_cast(unsigned short, (__bf16)x);
  unsigned short b = __builtin_bit_cast(unsigned short, (__bf16)y);
  return (unsigned)a | ((unsigned)b << 16);
}

// async global->LDS, 16B per lane
__device__ __forceinline__ void gl2lds16(const void* g, void* l) {
  __builtin_amdgcn_global_load_lds(
      (const __attribute__((address_space(1))) void*)g,
      (__attribute__((address_space(3))) void*)l,
      16, 0, 0);
}

// ---------------------------------------------------------------- prep
__global__ __launch_bounds__(256) void cast_f32_bf16(
    const float* __restrict__ in, unsigned short* __restrict__ out, int n) {
  int i = (blockIdx.x * 256 + threadIdx.x) * 4;
  if (i >= n) return;
  float4 v = *(const float4*)(in + i);
  u16x4 o;
  o[0] = f2bf(v.x); o[1] = f2bf(v.y); o[2] = f2bf(v.z); o[3] = f2bf(v.w);
  *(u16x4*)(out + i) = o;
}

__global__ __launch_bounds__(256) void transpose_cast(
    const float* __restrict__ in, unsigned short* __restrict__ out, int R, int C) {
  __shared__ float t[32][33];
  int c0 = blockIdx.x * 32, r0 = blockIdx.y * 32;
  int tx = threadIdx.x, ty = threadIdx.y;
#pragma unroll
  for (int j = 0; j < 4; ++j)
    t[ty + j * 8][tx] = in[(size_t)(r0 + ty + j * 8) * C + c0 + tx];
  __syncthreads();
#pragma unroll
  for (int j = 0; j < 4; ++j)
    out[(size_t)(c0 + ty + j * 8) * R + r0 + tx] = f2bf(t[tx][ty + j * 8]);
}

// key_padding_mask -> per-batch max unpadded key index+1 (suffix-mask semantics).
__global__ __launch_bounds__(256) void prep_pad(
    const int* __restrict__ mask, float* __restrict__ padd, int* __restrict__ kmax, int n) {
  int i = blockIdx.x * 256 + threadIdx.x;
  if (i >= n) return;
  int mv = mask[i];
  padd[i] = mv ? -1e30f : 0.0f;
  int key = mv ? 0 : ((i & 2047) + 1);
#pragma unroll
  for (int off = 32; off; off >>= 1) key = max(key, __shfl_xor(key, off, 64));
  if ((threadIdx.x & 63) == 0) atomicMax(&kmax[i >> 11], key);  // i>>11 wave-uniform
}

// ---------------------------------------------------------------- GEMM (C = A[M,K] * B[N,K]^T)
// Round 4: double-buffered LDS + prefetch-before-compute, ONE barrier per
// K-step (was: barrier; stage; barrier -> full staging latency exposed each
// step). Now the stage for step k+1 is issued before step k's compute; the
// compiler's vmcnt(0)-at-barrier drains it at the NEXT barrier, after the
// MFMA work -> latency hidden. LDS 16->32 KB.
template <int EPI>
__global__ __launch_bounds__(256) void gemm_bt(
    const unsigned short* __restrict__ A, const unsigned short* __restrict__ Bm,
    const float* __restrict__ bias, float* __restrict__ outF,
    unsigned short* __restrict__ Qb, unsigned short* __restrict__ Kb,
    unsigned short* __restrict__ Vt, int M, int N, int K) {
  __shared__ unsigned short As[2 * 128 * 32];
  __shared__ unsigned short Bs[2 * 128 * 32];
  const int tid = threadIdx.x;
  const int bm = blockIdx.x * 128;
  const int bn = blockIdx.y * 128;
  const int wave = tid >> 6, lane = tid & 63;
  const int wm = (wave >> 1) * 64, wn = (wave & 1) * 64;
  const int lr = lane & 15, lq = lane >> 4;

  f32x4 acc[4][4] = {};

  const int c0 = tid, c1 = tid + 256;
  const int rA0 = c0 >> 2, colA0 = (c0 & 3) * 8;
  const int rA1 = c1 >> 2, colA1 = (c1 & 3) * 8;

  auto stage = [&](int buf, int k0) {
    gl2lds16(A + (size_t)(bm + rA0) * K + k0 + colA0, As + buf * 4096 + c0 * 8);
    gl2lds16(A + (size_t)(bm + rA1) * K + k0 + colA1, As + buf * 4096 + c1 * 8);
    gl2lds16(Bm + (size_t)(bn + rA0) * K + k0 + colA0, Bs + buf * 4096 + c0 * 8);
    gl2lds16(Bm + (size_t)(bn + rA1) * K + k0 + colA1, Bs + buf * 4096 + c1 * 8);
  };

  stage(0, 0);
  int cur = 0;
  for (int k0 = 0; k0 < K; k0 += 32) {
    __syncthreads();  // buf[cur] staged (vmcnt drain); prev reads of buf[cur^1] done
    if (k0 + 32 < K) stage(cur ^ 1, k0 + 32);
    const unsigned short* Asb = As + cur * 4096;
    const unsigned short* Bsb = Bs + cur * 4096;
    bf16x8 af[4], bfr[4];
#pragma unroll
    for (int mi = 0; mi < 4; ++mi)
      af[mi] = *(const bf16x8*)(Asb + (wm + mi * 16 + lr) * 32 + lq * 8);
#pragma unroll
    for (int nj = 0; nj < 4; ++nj)
      bfr[nj] = *(const bf16x8*)(Bsb + (wn + nj * 16 + lr) * 32 + lq * 8);
#pragma unroll
    for (int mi = 0; mi < 4; ++mi)
#pragma unroll
      for (int nj = 0; nj < 4; ++nj)
        acc[mi][nj] = __builtin_amdgcn_mfma_f32_16x16x32_bf16(af[mi], bfr[nj], acc[mi][nj], 0, 0, 0);
    cur ^= 1;
  }

#pragma unroll
  for (int mi = 0; mi < 4; ++mi) {
#pragma unroll
    for (int nj = 0; nj < 4; ++nj) {
#pragma unroll
      for (int r = 0; r < 4; ++r) {
        int m = bm + wm + mi * 16 + lq * 4 + r;
        int n = bn + wn + nj * 16 + lr;
        float v = acc[mi][nj][r] + bias[n];
        if (EPI == 0) {
          int b = m >> 11, t = m & 2047;
          int part = n >> 10, d = n & 1023;
          int h = d >> 6, hd = d & 63;
          size_t qk = ((size_t)(b * 16 + h) * 2048 + t) * 64 + hd;
          // fold softmax scale 1/sqrt(64) and log2(e) into Q
          if (part == 0)      Qb[qk] = f2bf(v * 0.18033688011112042f);
          else if (part == 1) Kb[qk] = f2bf(v);
          else                Vt[((size_t)(b * 16 + h) * 64 + hd) * 2048 + t] = f2bf(v);
        } else {
          outF[(size_t)m * N + n] = v;
        }
      }
    }
  }
}

// ---------------------------------------------------------------- flash attention
// LDS-staged, double-buffered, 32x32 MFMA, lane-local softmax.
// Round 4: occupancy 2x. Was 512 blocks (2/CU, 2 waves/SIMD) with 64 q-rows
// per wave -> staging drain could only hide under one other block. Now 1024
// blocks of 128 q-rows, 4 waves x 32 q-rows (qt dimension dropped -> register
// state halves, fits 4 waves/SIMD). Same per-wave data path otherwise.
//  - per 64-key chunk: K tile [64k][64d] (8KB) + V tile [64hd][64k] (8KB)
//    staged via global_load_lds, double-buffered (32KB). XOR swizzle
//    (slot ^= row&7, 16B gran) on the GLOBAL source + on the ds_read side.
//  - S^T = K.Q^T via mfma_f32_32x32x16_bf16: q = lane&31 -> softmax stats
//    lane-local; O^T = V^T.P keeps q lane-local (no alpha broadcast).
__global__ __launch_bounds__(256, 4) void flash_attn(
    const unsigned short* __restrict__ Qb, const unsigned short* __restrict__ Kb,
    const unsigned short* __restrict__ Vt, const int* __restrict__ kmax,
    unsigned short* __restrict__ ctx) {
  __shared__ unsigned short lds[16384];  // [buf][ K 4096 | V 4096 ] elements

  const int bid = blockIdx.x;            // 1024 blocks
  const int halfg = bid >> 9;            // 0/1
  const int rb = bid & 511;
  const int bh = rb & 63;                // bid%8 == bh%8 -> XCD locality
  const int j0 = rb >> 6;                // 0..7
  const int j = halfg ? (15 - j0) : j0;  // q-superblock 0..15, paired for balance
  const int blockQ = j << 7;             // 128 q-rows per block
  const int b = bh >> 4, h = bh & 15;
  const int tid = threadIdx.x;
  const int wave = tid >> 6, lane = tid & 63;
  const int l31 = lane & 31, hi = lane >> 5;
  const int qw = blockQ + wave * 32;     // wave's 32 q-rows

  const unsigned short* Qh = Qb + (size_t)bh * 2048 * 64;
  const unsigned short* Kh = Kb + (size_t)bh * 2048 * 64;
  const unsigned short* Vh = Vt + (size_t)bh * 64 * 2048;
  unsigned short* ctxBase = ctx + (size_t)b * 2048 * 1024 + h * 64;

  const int kmaxRaw = kmax[b];
  const int kcapC = (kmaxRaw + 63) >> 6;                     // chunks by padding
  const int lastB = min((blockQ + 127) >> 6, kcapC - 1);     // block's last chunk
  const int diagI = qw >> 6;                                 // wave's diagonal chunk

  // Q fragments: B-operand of QK (n=q=l31, k=d=8*hi+j), 16B contiguous
  bf16x8 qf[4];
#pragma unroll
  for (int ds = 0; ds < 4; ++ds)
    qf[ds] = *(const bf16x8*)(Qh + (size_t)(qw + l31) * 64 + ds * 16 + hi * 8);

  f32x16 O[2] = {};                      // [mt]  O^T: row=hd(reg), col=q(lane)
  float mR = -1e30f, lR = 0.f;

  const int trow = tid >> 3, tslot = tid & 7;

  // stage one 64-key chunk (K 8KB + V 8KB) into buf; inverse-swizzled source
  auto stage = [&](int bufI, int kcS) {
#pragma unroll
    for (int rnd = 0; rnd < 2; ++rnd) {
      int row = rnd * 32 + trow;
      int sl = tslot ^ (row & 7);
      gl2lds16(Kh + (size_t)(kcS + row) * 64 + sl * 8,
               lds + bufI * 8192 + rnd * 2048 + tid * 8);
      gl2lds16(Vh + (size_t)row * 2048 + kcS + sl * 8,
               lds + bufI * 8192 + 4096 + rnd * 2048 + tid * 8);
    }
  };

  stage(0, 0);
  int cur = 0;
  for (int i = 0; i <= lastB; ++i) {
    __syncthreads();  // buf[cur] staged; prior reads of buf[cur^1] done
    if (i < lastB) stage(cur ^ 1, (i + 1) << 6);
    if (i <= diagI) {
      const int kc = i << 6;
      const unsigned short* Ksb = lds + cur * 8192;
      const unsigned short* Vsb = Ksb + 4096;

      // ---- QK^T: S^T[key][q], A=K (m=key), B=Q^T (n=q)
      f32x16 S[2] = {};  // [kt]
      __builtin_amdgcn_s_setprio(1);
#pragma unroll
      for (int kt = 0; kt < 2; ++kt) {
        const int row = kt * 32 + l31;
        const int rx = row & 7;
#pragma unroll
        for (int ds = 0; ds < 4; ++ds) {
          bf16x8 kfr = *(const bf16x8*)(Ksb + row * 64 + (((ds * 2 + hi) ^ rx) << 3));
          S[kt] = __builtin_amdgcn_mfma_f32_32x32x16_bf16(kfr, qf[ds], S[kt], 0, 0, 0);
        }
      }
      __builtin_amdgcn_s_setprio(0);

      // ---- mask (causal on diag chunk; padding on boundary chunk)
      const bool isDiag = (i == diagI);
      if (isDiag || (kc + 64 > kmaxRaw)) {
        const int q = qw + l31;
#pragma unroll
        for (int kt = 0; kt < 2; ++kt)
#pragma unroll
          for (int rr = 0; rr < 16; ++rr) {
            int key = kc + kt * 32 + (rr & 3) + ((rr >> 2) << 3) + (hi << 2);
            if ((isDiag && key > q) || key >= kmaxRaw) S[kt][rr] = -1e30f;
          }
      }

      // ---- online softmax (q lane-local) + P pack
      {
        float v[16];
#pragma unroll
        for (int rr = 0; rr < 16; ++rr) v[rr] = fmaxf(S[0][rr], S[1][rr]);
#pragma unroll
        for (int st = 8; st; st >>= 1)
#pragma unroll
          for (int rr = 0; rr < st; ++rr) v[rr] = fmaxf(v[rr], v[rr + st]);
        float mx = fmaxf(v[0], __shfl_xor(v[0], 32, 64));
        float mnew = fmaxf(mR, mx);
        float a = __builtin_amdgcn_exp2f(mR - mnew);
        mR = mnew;
#pragma unroll
        for (int kt = 0; kt < 2; ++kt)
#pragma unroll
          for (int rr = 0; rr < 16; ++rr)
            S[kt][rr] = __builtin_amdgcn_exp2f(S[kt][rr] - mnew);
        float sacc[16];
#pragma unroll
        for (int rr = 0; rr < 16; ++rr) sacc[rr] = S[0][rr] + S[1][rr];
#pragma unroll
        for (int st = 8; st; st >>= 1)
#pragma unroll
          for (int rr = 0; rr < st; ++rr) sacc[rr] += sacc[rr + st];
        float sum = sacc[0] + __shfl_xor(sacc[0], 32, 64);
        lR = lR * a + sum;
#pragma unroll
        for (int mt = 0; mt < 2; ++mt)
#pragma unroll
          for (int rr = 0; rr < 16; ++rr) O[mt][rr] *= a;
      }
      // pack P into PV B-frags (n=q=l31, k=key=8*hi+j within 16-key step)
      bf16x8 pf[2][2];  // [kt][ks]
#pragma unroll
      for (int kt = 0; kt < 2; ++kt) {
        unsigned a0 = pkbf(S[kt][0], S[kt][1]);
        unsigned a1 = pkbf(S[kt][2], S[kt][3]);
        unsigned b0 = pkbf(S[kt][4], S[kt][5]);
        unsigned b1 = pkbf(S[kt][6], S[kt][7]);
        unsigned c0 = pkbf(S[kt][8], S[kt][9]);
        unsigned c1 = pkbf(S[kt][10], S[kt][11]);
        unsigned d0 = pkbf(S[kt][12], S[kt][13]);
        unsigned d1 = pkbf(S[kt][14], S[kt][15]);
        unsigned s0 = __shfl_xor(hi ? a0 : b0, 32, 64);
        unsigned s1 = __shfl_xor(hi ? a1 : b1, 32, 64);
        unsigned s2 = __shfl_xor(hi ? c0 : d0, 32, 64);
        unsigned s3 = __shfl_xor(hi ? c1 : d1, 32, 64);
        u32x4 f0, f1;
        f0[0] = hi ? s0 : a0; f0[1] = hi ? s1 : a1;
        f0[2] = hi ? b0 : s0; f0[3] = hi ? b1 : s1;
        f1[0] = hi ? s2 : c0; f1[1] = hi ? s3 : c1;
        f1[2] = hi ? d0 : s2; f1[3] = hi ? d1 : s3;
        pf[kt][0] = __builtin_bit_cast(bf16x8, f0);
        pf[kt][1] = __builtin_bit_cast(bf16x8, f1);
      }

      // ---- PV: O^T += V^T . P   (A=V^T: m=hd, k=key; B=P)
      __builtin_amdgcn_s_setprio(1);
      const int vx = l31 & 7;
#pragma unroll
      for (int kt = 0; kt < 2; ++kt)
#pragma unroll
        for (int ks = 0; ks < 2; ++ks) {
          const int slot = kt * 4 + ks * 2 + hi;
          bf16x8 v0 = *(const bf16x8*)(Vsb + l31 * 64 + ((slot ^ vx) << 3));
          bf16x8 v1 = *(const bf16x8*)(Vsb + (32 + l31) * 64 + ((slot ^ vx) << 3));
          O[0] = __builtin_amdgcn_mfma_f32_32x32x16_bf16(v0, pf[kt][ks], O[0], 0, 0, 0);
          O[1] = __builtin_amdgcn_mfma_f32_32x32x16_bf16(v1, pf[kt][ks], O[1], 0, 0, 0);
        }
      __builtin_amdgcn_s_setprio(0);
    }
    cur ^= 1;
  }

  // ---- epilogue: O^T normalize, write ctx[q][h*64+hd] (q lane-local)
  {
    float linv = 1.0f / lR;
    const int q = qw + l31;
    unsigned short* cp = ctxBase + (size_t)q * 1024;
#pragma unroll
    for (int mt = 0; mt < 2; ++mt)
#pragma unroll
      for (int g = 0; g < 4; ++g) {
        u16x4 o4;
#pragma unroll
        for (int rr = 0; rr < 4; ++rr) o4[rr] = f2bf(O[mt][4 * g + rr] * linv);
        *(u16x4*)(cp + mt * 32 + 8 * g + 4 * hi) = o4;
      }
  }
}

// ---------------------------------------------------------------- launch
extern "C" void kernel_launch(void* const* d_in, const int* in_sizes, int n_in,
                              void* d_out, int out_size, void* d_ws, size_t ws_size,
                              hipStream_t stream) {
  const float* x    = (const float*)d_in[0];
  const float* Wqkv = (const float*)d_in[1];
  const float* bqkv = (const float*)d_in[2];
  const float* Wo   = (const float*)d_in[3];
  const float* bo   = (const float*)d_in[4];
  const int*   mask = (const int*)d_in[5];
  float* out = (float*)d_out;

  unsigned short* ws = (unsigned short*)d_ws;
  const size_t SZ_X = (size_t)8192 * 1024;  // B*T*D
  unsigned short* xb    = ws;                                   // 16 MB, reused as ctx
  unsigned short* WqkvT = xb + SZ_X;                            // 6 MB
  unsigned short* WoT   = WqkvT + (size_t)3072 * 1024;          // 2 MB
  unsigned short* Qb    = WoT + (size_t)1024 * 1024;            // 16 MB
  unsigned short* Kb    = Qb + SZ_X;                            // 16 MB
  unsigned short* Vt    = Kb + SZ_X;                            // 16 MB
  float*          padd  = (float*)(Vt + SZ_X);                  // 32 KB
  int*            kmax  = (int*)(padd + 8192);                  // 16 B
  unsigned short* ctx   = xb;  // xb dead after GEMM1

  hipMemsetAsync(kmax, 0, 4 * sizeof(int), stream);
  cast_f32_bf16<<<8192, 256, 0, stream>>>(x, xb, (int)SZ_X);
  transpose_cast<<<dim3(96, 32), dim3(32, 8), 0, stream>>>(Wqkv, WqkvT, 1024, 3072);
  transpose_cast<<<dim3(32, 32), dim3(32, 8), 0, stream>>>(Wo, WoT, 1024, 1024);
  prep_pad<<<32, 256, 0, stream>>>(mask, padd, kmax, 8192);
  gemm_bt<0><<<dim3(64, 24), 256, 0, stream>>>(xb, WqkvT, bqkv, nullptr, Qb, Kb, Vt,
                                               8192, 3072, 1024);
  flash_attn<<<1024, 256, 0, stream>>>(Qb, Kb, Vt, kmax, ctx);
  gemm_bt<1><<<dim3(64, 8), 256, 0, stream>>>(ctx, WoT, bo, out, nullptr, nullptr, nullptr,
                                              8192, 1024, 1024);
}

// Round 5
// 261.647 us; speedup vs baseline: 1.5530x; 1.0461x over previous
//
#include <hip/hip_runtime.h>
#include <cstdint>
#include <cstddef>

typedef __bf16 bf16x8 __attribute__((ext_vector_type(8)));
typedef float f32x4 __attribute__((ext_vector_type(4)));
typedef float f32x16 __attribute__((ext_vector_type(16)));
typedef unsigned short u16x4 __attribute__((ext_vector_type(4)));
typedef unsigned int u32x4 __attribute__((ext_vector_type(4)));

// fp32 -> bf16 round-to-nearest-even
__device__ __forceinline__ unsigned short f2bf(float f) {
  union { float f; unsigned u; } v; v.f = f;
  unsigned r = (v.u + 0x7FFF + ((v.u >> 16) & 1)) >> 16;
  return (unsigned short)r;
}

// pack two floats into one u32 of 2 bf16
__device__ __forceinline__ unsigned pkbf(float x, float y) {
  unsigned short a = __builtin_bit_cast(unsigned short, (__bf16)x);
  unsigned short b = __builtin_bit_cast(unsigned short, (__bf16)y);
  return (unsigned)a | ((unsigned)b << 16);
}

// async global->LDS, 16B per lane
__device__ __forceinline__ void gl2lds16(const void* g, void* l) {
  __builtin_amdgcn_global_load_lds(
      (const __attribute__((address_space(1))) void*)g,
      (__attribute__((address_space(3))) void*)l,
      16, 0, 0);
}

// ---------------------------------------------------------------- fused prep
// Round 5: one kernel instead of 4 (cast, 2 transposes, kmax) -> saves ~3
// inter-dispatch gaps (~8us each measured by subtraction).
__global__ __launch_bounds__(256) void prep_fused(
    const float* __restrict__ x, unsigned short* __restrict__ xb,
    const float* __restrict__ Wqkv, unsigned short* __restrict__ WqkvT,
    const float* __restrict__ Wo, unsigned short* __restrict__ WoT,
    const int* __restrict__ mask, int* __restrict__ kmax) {
  __shared__ float t[32][33];
  const int bid = blockIdx.x, tid = threadIdx.x;
  if (bid < 4096) {
    // cast x -> bf16, 2 chunks of 4 floats per thread
    size_t i = ((size_t)bid * 256 + tid) * 4;
#pragma unroll
    for (int c = 0; c < 2; ++c) {
      float4 v = *(const float4*)(x + i);
      u16x4 o;
      o[0] = f2bf(v.x); o[1] = f2bf(v.y); o[2] = f2bf(v.z); o[3] = f2bf(v.w);
      *(u16x4*)(xb + i) = o;
      i += (size_t)4096 * 256 * 4;
    }
  } else if (bid < 4096 + 3072) {
    // transpose+cast Wqkv [1024,3072] -> WqkvT [3072,1024]
    const int b2 = bid - 4096;
    const int c0 = (b2 % 96) * 32, r0 = (b2 / 96) * 32;
    const int tx = tid & 31, ty = tid >> 5;
#pragma unroll
    for (int j = 0; j < 4; ++j)
      t[ty + j * 8][tx] = Wqkv[(size_t)(r0 + ty + j * 8) * 3072 + c0 + tx];
    __syncthreads();
#pragma unroll
    for (int j = 0; j < 4; ++j)
      WqkvT[(size_t)(c0 + ty + j * 8) * 1024 + r0 + tx] = f2bf(t[tx][ty + j * 8]);
  } else if (bid < 8192) {
    // transpose+cast Wo [1024,1024] -> WoT
    const int b3 = bid - (4096 + 3072);
    const int c0 = (b3 & 31) * 32, r0 = (b3 >> 5) * 32;
    const int tx = tid & 31, ty = tid >> 5;
#pragma unroll
    for (int j = 0; j < 4; ++j)
      t[ty + j * 8][tx] = Wo[(size_t)(r0 + ty + j * 8) * 1024 + c0 + tx];
    __syncthreads();
#pragma unroll
    for (int j = 0; j < 4; ++j)
      WoT[(size_t)(c0 + ty + j * 8) * 1024 + r0 + tx] = f2bf(t[tx][ty + j * 8]);
  } else {
    // per-batch max unpadded key index+1 (suffix-mask semantics)
    const int i = (bid - 8192) * 256 + tid;
    int mv = mask[i];
    int key = mv ? 0 : ((i & 2047) + 1);
#pragma unroll
    for (int off = 32; off; off >>= 1) key = max(key, __shfl_xor(key, off, 64));
    if ((tid & 63) == 0) atomicMax(&kmax[i >> 11], key);
  }
}

// ---------------------------------------------------------------- GEMM (C = A[M,K] * B[N,K]^T)
// Round 5 rewrite: BM=256 x BN=128 x BK=64, 512 threads (8 waves = 4m x 2n,
// 64x64 out each), THREE LDS K-tile buffers (48KB each, 144KB dynamic LDS),
// counted-vmcnt software pipeline:
//   per tile T: s_waitcnt vmcnt(6) [T landed; T+1's 6 loads stay in flight,
//   NEVER drain to 0 in-loop] -> s_barrier -> issue T+2 into buf[(T+2)%3]
//   (occupant T-1 provably dead: all waves passed this barrier after
//   finishing T-1's reads) -> ds_read frags + MFMA (setprio around cluster).
// BK=64 -> 128B LDS rows -> full T2 XOR swizzle (slot ^= row&7) applied on the
// GLOBAL source (gl2lds dest stays linear) and on the ds_read side: even
// 8-lane-per-16B-position spread -> conflict-free b128.
template <int EPI>
__global__ __launch_bounds__(512, 2) void gemm_bt(
    const unsigned short* __restrict__ A, const unsigned short* __restrict__ Bm,
    const float* __restrict__ bias, float* __restrict__ outF,
    unsigned short* __restrict__ Qb, unsigned short* __restrict__ Kb,
    unsigned short* __restrict__ Vt, int M, int N, int K) {
  extern __shared__ unsigned short lds[];  // 3 bufs x (A 16384 + B 8192) els
  const int tid = threadIdx.x;
  const int bm = blockIdx.x * 256;
  const int bn = blockIdx.y * 128;
  const int wave = tid >> 6, lane = tid & 63;
  const int wm4 = wave >> 1, wn2 = wave & 1;   // 4 m-waves x 2 n-waves
  const int lr = lane & 15, lq = lane >> 4;
  const int NT = K >> 6;

  f32x4 acc[4][4] = {};

  const int tr = tid >> 3, ts = tid & 7;
  const int srcsl = (ts ^ (tr & 7)) << 3;      // pre-swizzled global slot (els)

  auto stage = [&](int buf, int k0) {
#pragma unroll
    for (int r = 0; r < 4; ++r) {
      int row = r * 64 + tr;
      gl2lds16(A + (size_t)(bm + row) * K + k0 + srcsl,
               lds + buf * 24576 + r * 4096 + tid * 8);
    }
#pragma unroll
    for (int r = 0; r < 2; ++r) {
      int row = r * 64 + tr;
      gl2lds16(Bm + (size_t)(bn + row) * K + k0 + srcsl,
               lds + buf * 24576 + 16384 + r * 4096 + tid * 8);
    }
  };

  stage(0, 0);
  stage(1, 64);
  int bT = 0, bT2 = 2;
  const int rx = lr & 7;  // read-side swizzle key (row&7 == lr&7 here)
  for (int T = 0; T < NT; ++T) {
    if (T < NT - 1) {
      asm volatile("s_waitcnt vmcnt(6)" ::: "memory");
    } else {
      asm volatile("s_waitcnt vmcnt(0)" ::: "memory");
    }
    __builtin_amdgcn_s_barrier();
    __builtin_amdgcn_sched_barrier(0);
    if (T + 2 < NT) stage(bT2, (T + 2) << 6);
    const unsigned short* Ab = lds + bT * 24576;
    const unsigned short* Bb = Ab + 16384;
#pragma unroll
    for (int ks = 0; ks < 2; ++ks) {
      bf16x8 afr[4], bfr[4];
#pragma unroll
      for (int mi = 0; mi < 4; ++mi) {
        int row = wm4 * 64 + mi * 16 + lr;
        afr[mi] = *(const bf16x8*)(Ab + row * 64 + ((((ks << 2) | lq) ^ rx) << 3));
      }
#pragma unroll
      for (int nj = 0; nj < 4; ++nj) {
        int row = wn2 * 64 + nj * 16 + lr;
        bfr[nj] = *(const bf16x8*)(Bb + row * 64 + ((((ks << 2) | lq) ^ rx) << 3));
      }
      __builtin_amdgcn_s_setprio(1);
#pragma unroll
      for (int mi = 0; mi < 4; ++mi)
#pragma unroll
        for (int nj = 0; nj < 4; ++nj)
          acc[mi][nj] = __builtin_amdgcn_mfma_f32_16x16x32_bf16(afr[mi], bfr[nj], acc[mi][nj], 0, 0, 0);
      __builtin_amdgcn_s_setprio(0);
    }
    bT = (bT == 2) ? 0 : bT + 1;
    bT2 = (bT2 == 2) ? 0 : bT2 + 1;
  }

#pragma unroll
  for (int mi = 0; mi < 4; ++mi) {
#pragma unroll
    for (int nj = 0; nj < 4; ++nj) {
#pragma unroll
      for (int r = 0; r < 4; ++r) {
        int m = bm + wm4 * 64 + mi * 16 + lq * 4 + r;
        int n = bn + wn2 * 64 + nj * 16 + lr;
        float v = acc[mi][nj][r] + bias[n];
        if (EPI == 0) {
          int b = m >> 11, t = m & 2047;
          int part = n >> 10, d = n & 1023;
          int h = d >> 6, hd = d & 63;
          size_t qk = ((size_t)(b * 16 + h) * 2048 + t) * 64 + hd;
          // fold softmax scale 1/sqrt(64) and log2(e) into Q
          if (part == 0)      Qb[qk] = f2bf(v * 0.18033688011112042f);
          else if (part == 1) Kb[qk] = f2bf(v);
          else                Vt[((size_t)(b * 16 + h) * 64 + hd) * 2048 + t] = f2bf(v);
        } else {
          outF[(size_t)m * N + n] = v;
        }
      }
    }
  }
}

// ---------------------------------------------------------------- flash attention
// (unchanged from round 4: LDS-staged dbuf, 32x32 MFMA, lane-local softmax,
// 1024 blocks of 4 waves x 32 q-rows, 4 blocks/CU)
__global__ __launch_bounds__(256, 4) void flash_attn(
    const unsigned short* __restrict__ Qb, const unsigned short* __restrict__ Kb,
    const unsigned short* __restrict__ Vt, const int* __restrict__ kmax,
    unsigned short* __restrict__ ctx) {
  __shared__ unsigned short lds[16384];  // [buf][ K 4096 | V 4096 ] elements

  const int bid = blockIdx.x;            // 1024 blocks
  const int halfg = bid >> 9;            // 0/1
  const int rb = bid & 511;
  const int bh = rb & 63;                // bid%8 == bh%8 -> XCD locality
  const int j0 = rb >> 6;                // 0..7
  const int j = halfg ? (15 - j0) : j0;  // q-superblock 0..15, paired for balance
  const int blockQ = j << 7;             // 128 q-rows per block
  const int b = bh >> 4, h = bh & 15;
  const int tid = threadIdx.x;
  const int wave = tid >> 6, lane = tid & 63;
  const int l31 = lane & 31, hi = lane >> 5;
  const int qw = blockQ + wave * 32;     // wave's 32 q-rows

  const unsigned short* Qh = Qb + (size_t)bh * 2048 * 64;
  const unsigned short* Kh = Kb + (size_t)bh * 2048 * 64;
  const unsigned short* Vh = Vt + (size_t)bh * 64 * 2048;
  unsigned short* ctxBase = ctx + (size_t)b * 2048 * 1024 + h * 64;

  const int kmaxRaw = kmax[b];
  const int kcapC = (kmaxRaw + 63) >> 6;                     // chunks by padding
  const int lastB = min((blockQ + 127) >> 6, kcapC - 1);     // block's last chunk
  const int diagI = qw >> 6;                                 // wave's diagonal chunk

  bf16x8 qf[4];
#pragma unroll
  for (int ds = 0; ds < 4; ++ds)
    qf[ds] = *(const bf16x8*)(Qh + (size_t)(qw + l31) * 64 + ds * 16 + hi * 8);

  f32x16 O[2] = {};                      // [mt]  O^T: row=hd(reg), col=q(lane)
  float mR = -1e30f, lR = 0.f;

  const int trow = tid >> 3, tslot = tid & 7;

  auto stage = [&](int bufI, int kcS) {
#pragma unroll
    for (int rnd = 0; rnd < 2; ++rnd) {
      int row = rnd * 32 + trow;
      int sl = tslot ^ (row & 7);
      gl2lds16(Kh + (size_t)(kcS + row) * 64 + sl * 8,
               lds + bufI * 8192 + rnd * 2048 + tid * 8);
      gl2lds16(Vh + (size_t)row * 2048 + kcS + sl * 8,
               lds + bufI * 8192 + 4096 + rnd * 2048 + tid * 8);
    }
  };

  stage(0, 0);
  int cur = 0;
  for (int i = 0; i <= lastB; ++i) {
    __syncthreads();  // buf[cur] staged; prior reads of buf[cur^1] done
    if (i < lastB) stage(cur ^ 1, (i + 1) << 6);
    if (i <= diagI) {
      const int kc = i << 6;
      const unsigned short* Ksb = lds + cur * 8192;
      const unsigned short* Vsb = Ksb + 4096;

      // ---- QK^T: S^T[key][q], A=K (m=key), B=Q^T (n=q)
      f32x16 S[2] = {};  // [kt]
      __builtin_amdgcn_s_setprio(1);
#pragma unroll
      for (int kt = 0; kt < 2; ++kt) {
        const int row = kt * 32 + l31;
        const int rx = row & 7;
#pragma unroll
        for (int ds = 0; ds < 4; ++ds) {
          bf16x8 kfr = *(const bf16x8*)(Ksb + row * 64 + (((ds * 2 + hi) ^ rx) << 3));
          S[kt] = __builtin_amdgcn_mfma_f32_32x32x16_bf16(kfr, qf[ds], S[kt], 0, 0, 0);
        }
      }
      __builtin_amdgcn_s_setprio(0);

      // ---- mask (causal on diag chunk; padding on boundary chunk)
      const bool isDiag = (i == diagI);
      if (isDiag || (kc + 64 > kmaxRaw)) {
        const int q = qw + l31;
#pragma unroll
        for (int kt = 0; kt < 2; ++kt)
#pragma unroll
          for (int rr = 0; rr < 16; ++rr) {
            int key = kc + kt * 32 + (rr & 3) + ((rr >> 2) << 3) + (hi << 2);
            if ((isDiag && key > q) || key >= kmaxRaw) S[kt][rr] = -1e30f;
          }
      }

      // ---- online softmax (q lane-local)
      {
        float v[16];
#pragma unroll
        for (int rr = 0; rr < 16; ++rr) v[rr] = fmaxf(S[0][rr], S[1][rr]);
#pragma unroll
        for (int st = 8; st; st >>= 1)
#pragma unroll
          for (int rr = 0; rr < st; ++rr) v[rr] = fmaxf(v[rr], v[rr + st]);
        float mx = fmaxf(v[0], __shfl_xor(v[0], 32, 64));
        float mnew = fmaxf(mR, mx);
        float a = __builtin_amdgcn_exp2f(mR - mnew);
        mR = mnew;
#pragma unroll
        for (int kt = 0; kt < 2; ++kt)
#pragma unroll
          for (int rr = 0; rr < 16; ++rr)
            S[kt][rr] = __builtin_amdgcn_exp2f(S[kt][rr] - mnew);
        float sacc[16];
#pragma unroll
        for (int rr = 0; rr < 16; ++rr) sacc[rr] = S[0][rr] + S[1][rr];
#pragma unroll
        for (int st = 8; st; st >>= 1)
#pragma unroll
          for (int rr = 0; rr < st; ++rr) sacc[rr] += sacc[rr + st];
        float sum = sacc[0] + __shfl_xor(sacc[0], 32, 64);
        lR = lR * a + sum;
#pragma unroll
        for (int mt = 0; mt < 2; ++mt)
#pragma unroll
          for (int rr = 0; rr < 16; ++rr) O[mt][rr] *= a;
      }
      // pack P into PV B-frags (n=q=l31, k=key=8*hi+j within 16-key step)
      bf16x8 pf[2][2];  // [kt][ks]
#pragma unroll
      for (int kt = 0; kt < 2; ++kt) {
        unsigned a0 = pkbf(S[kt][0], S[kt][1]);
        unsigned a1 = pkbf(S[kt][2], S[kt][3]);
        unsigned b0 = pkbf(S[kt][4], S[kt][5]);
        unsigned b1 = pkbf(S[kt][6], S[kt][7]);
        unsigned c0 = pkbf(S[kt][8], S[kt][9]);
        unsigned c1 = pkbf(S[kt][10], S[kt][11]);
        unsigned d0 = pkbf(S[kt][12], S[kt][13]);
        unsigned d1 = pkbf(S[kt][14], S[kt][15]);
        unsigned s0 = __shfl_xor(hi ? a0 : b0, 32, 64);
        unsigned s1 = __shfl_xor(hi ? a1 : b1, 32, 64);
        unsigned s2 = __shfl_xor(hi ? c0 : d0, 32, 64);
        unsigned s3 = __shfl_xor(hi ? c1 : d1, 32, 64);
        u32x4 f0, f1;
        f0[0] = hi ? s0 : a0; f0[1] = hi ? s1 : a1;
        f0[2] = hi ? b0 : s0; f0[3] = hi ? b1 : s1;
        f1[0] = hi ? s2 : c0; f1[1] = hi ? s3 : c1;
        f1[2] = hi ? d0 : s2; f1[3] = hi ? d1 : s3;
        pf[kt][0] = __builtin_bit_cast(bf16x8, f0);
        pf[kt][1] = __builtin_bit_cast(bf16x8, f1);
      }

      // ---- PV: O^T += V^T . P   (A=V^T: m=hd, k=key; B=P)
      __builtin_amdgcn_s_setprio(1);
      const int vx = l31 & 7;
#pragma unroll
      for (int kt = 0; kt < 2; ++kt)
#pragma unroll
        for (int ks = 0; ks < 2; ++ks) {
          const int slot = kt * 4 + ks * 2 + hi;
          bf16x8 v0 = *(const bf16x8*)(Vsb + l31 * 64 + ((slot ^ vx) << 3));
          bf16x8 v1 = *(const bf16x8*)(Vsb + (32 + l31) * 64 + ((slot ^ vx) << 3));
          O[0] = __builtin_amdgcn_mfma_f32_32x32x16_bf16(v0, pf[kt][ks], O[0], 0, 0, 0);
          O[1] = __builtin_amdgcn_mfma_f32_32x32x16_bf16(v1, pf[kt][ks], O[1], 0, 0, 0);
        }
      __builtin_amdgcn_s_setprio(0);
    }
    cur ^= 1;
  }

  // ---- epilogue: O^T normalize, write ctx[q][h*64+hd] (q lane-local)
  {
    float linv = 1.0f / lR;
    const int q = qw + l31;
    unsigned short* cp = ctxBase + (size_t)q * 1024;
#pragma unroll
    for (int mt = 0; mt < 2; ++mt)
#pragma unroll
      for (int g = 0; g < 4; ++g) {
        u16x4 o4;
#pragma unroll
        for (int rr = 0; rr < 4; ++rr) o4[rr] = f2bf(O[mt][4 * g + rr] * linv);
        *(u16x4*)(cp + mt * 32 + 8 * g + 4 * hi) = o4;
      }
  }
}

// ---------------------------------------------------------------- launch
extern "C" void kernel_launch(void* const* d_in, const int* in_sizes, int n_in,
                              void* d_out, int out_size, void* d_ws, size_t ws_size,
                              hipStream_t stream) {
  const float* x    = (const float*)d_in[0];
  const float* Wqkv = (const float*)d_in[1];
  const float* bqkv = (const float*)d_in[2];
  const float* Wo   = (const float*)d_in[3];
  const float* bo   = (const float*)d_in[4];
  const int*   mask = (const int*)d_in[5];
  float* out = (float*)d_out;

  unsigned short* ws = (unsigned short*)d_ws;
  const size_t SZ_X = (size_t)8192 * 1024;  // B*T*D
  unsigned short* xb    = ws;                                   // 16 MB, reused as ctx
  unsigned short* WqkvT = xb + SZ_X;                            // 6 MB
  unsigned short* WoT   = WqkvT + (size_t)3072 * 1024;          // 2 MB
  unsigned short* Qb    = WoT + (size_t)1024 * 1024;            // 16 MB
  unsigned short* Kb    = Qb + SZ_X;                            // 16 MB
  unsigned short* Vt    = Kb + SZ_X;                            // 16 MB
  int*            kmax  = (int*)(Vt + SZ_X);                    // 16 B
  unsigned short* ctx   = xb;  // xb dead after GEMM1

  static bool inited = false;
  if (!inited) {
    hipFuncSetAttribute((const void*)gemm_bt<0>,
                        hipFuncAttributeMaxDynamicSharedMemorySize, 147456);
    hipFuncSetAttribute((const void*)gemm_bt<1>,
                        hipFuncAttributeMaxDynamicSharedMemorySize, 147456);
    inited = true;
  }

  hipMemsetAsync(kmax, 0, 4 * sizeof(int), stream);
  prep_fused<<<8224, 256, 0, stream>>>(x, xb, Wqkv, WqkvT, Wo, WoT, mask, kmax);
  gemm_bt<0><<<dim3(32, 24), 512, 147456, stream>>>(xb, WqkvT, bqkv, nullptr, Qb, Kb, Vt,
                                                    8192, 3072, 1024);
  flash_attn<<<1024, 256, 0, stream>>>(Qb, Kb, Vt, kmax, ctx);
  gemm_bt<1><<<dim3(32, 8), 512, 147456, stream>>>(ctx, WoT, bo, out, nullptr, nullptr, nullptr,
                                                   8192, 1024, 1024);
}